// Round 1
// 736.812 us; speedup vs baseline: 1.0597x; 1.0597x over previous
//
#include <hip/hip_runtime.h>

// ---------------- problem constants ----------------
#define B_N 4096
#define D_N 10000
#define H_N 128
#define Z_N 32
#define K_N 16
#define KPAD 10240      // K padded for f16 MFMA gemm1 (8 slices of 1280)
#define KSLICE 1280

// d_out float offsets (outputs concatenated flat, all float32; k written as float)
#define OUT_XE 0ull
#define OUT_XQ 40960000ull
#define OUT_ZE 81920000ull
#define OUT_ZQ 82051072ull
#define OUT_K  82182144ull
#define OUT_ZD 82186240ull
#define OUT_DP 82251776ull

// ws byte offsets
#define WS_PART 0ull                // 8*4096*128*4 = 16777216
#define WS_H1   16777216ull         // 4096*128*4   = 2097152
#define WS_HE   18874368ull         // bf16 4096*128*2 = 1048576
#define WS_HQ   19922944ull         // 1048576
#define WS_W2TE 20971520ull         // bf16 10048*128*2 = 2572288
#define WS_W2TQ 23543808ull         // 2572288  (end 26116096 ~ 25 MB)
// w1T hi/lo (f16, 128*10240*2 = 2621440 B each) live in d_out[OUT_XE..],
// which is only written by dec2_kernel (the final kernel) -- safe in stream order.

typedef short bf16x8 __attribute__((ext_vector_type(8)));
typedef _Float16 half8 __attribute__((ext_vector_type(8)));
typedef float f32x4  __attribute__((ext_vector_type(4)));

static __device__ __forceinline__ unsigned short f2bf(float f) {
    union { float f; unsigned u; } v; v.f = f;
    return (unsigned short)((v.u + 0x7fffu + ((v.u >> 16) & 1u)) >> 16);
}

// ---------------- kernel 1a: transpose + cvt dec_*_w2 [128][10000] f32 -> w2T [10048][128] bf16 ----
__global__ __launch_bounds__(256) void transpose_cvt_kernel(
        const float* __restrict__ we, const float* __restrict__ wq,
        unsigned* __restrict__ oe, unsigned* __restrict__ oq) {
    const float* w2 = blockIdx.y ? wq : we;
    unsigned* o = blockIdx.y ? oq : oe;
    __shared__ float lds[64 * 129];
    const int n0 = blockIdx.x * 64;
    const int t = threadIdx.x;
#pragma unroll
    for (int i = 0; i < 32; ++i) {
        int idx = t + 256 * i;
        int k = idx >> 6, n = idx & 63;
        float v = (n0 + n < D_N) ? w2[(size_t)k * D_N + n0 + n] : 0.f;
        lds[n * 129 + k] = v;
    }
    __syncthreads();
#pragma unroll
    for (int i = 0; i < 16; ++i) {
        int idx = t + 256 * i;
        int n = idx >> 6, c = idx & 63;
        unsigned lo = f2bf(lds[n * 129 + 2 * c]);
        unsigned hi = f2bf(lds[n * 129 + 2 * c + 1]);
        o[(size_t)(n0 + n) * 64 + c] = lo | (hi << 16);
    }
}

// ---------------- kernel 1b: transpose + f16 hi/lo split of enc_w1 ----------------
// w1 [10000][128] f32 -> w1Th, w1Tl [128][10240] f16, values pre-scaled by 2^11.
// Zero-padded to KPAD so gemm1 needs no B-side bounds checks.
__global__ __launch_bounds__(256) void w1t_kernel(
        const float* __restrict__ w1, unsigned* __restrict__ th, unsigned* __restrict__ tl) {
    __shared__ float lds[128 * 66];
    const int t = threadIdx.x;
    const int d0 = blockIdx.x * 64;
#pragma unroll
    for (int i = 0; i < 32; ++i) {
        int idx = t + 256 * i;
        int dl = idx >> 7, h = idx & 127;
        float v = (d0 + dl < D_N) ? w1[(size_t)(d0 + dl) * H_N + h] : 0.f;
        lds[h * 66 + dl] = v;
    }
    __syncthreads();
#pragma unroll
    for (int i = 0; i < 16; ++i) {
        int idx = t + 256 * i;
        int h = idx >> 5, c = idx & 31;
        float f0 = lds[h * 66 + 2 * c]     * 2048.f;
        float f1 = lds[h * 66 + 2 * c + 1] * 2048.f;
        _Float16 h0 = (_Float16)f0, h1 = (_Float16)f1;
        _Float16 l0 = (_Float16)(f0 - (float)h0);
        _Float16 l1 = (_Float16)(f1 - (float)h1);
        union { _Float16 hh[2]; unsigned u; } ph, pl;
        ph.hh[0] = h0; ph.hh[1] = h1;
        pl.hh[0] = l0; pl.hh[1] = l1;
        size_t o = (size_t)h * (KPAD / 2) + blockIdx.x * 32 + c;
        th[o] = ph.u;
        tl[o] = pl.u;
    }
}

// ---------------- kernel 2: encoder L1 split-K GEMM via f16 hi/lo MFMA ----------------
// C = X @ W1 with X,W1 each split into fp16 hi+lo (pre-scaled 2^11); 3 MFMA passes
// give ~2^-22 per-term relative error == fp32-class accuracy (argmax-safe).
// grid (64 Mtiles, 8 Kslices of 1280), block 256 = 4 waves; wave = 16 rows x 128 cols.
__global__ __launch_bounds__(256) void gemm1_kernel(
        const float* __restrict__ x,
        const unsigned short* __restrict__ w1th,
        const unsigned short* __restrict__ w1tl,
        float* __restrict__ part) {
    const int t = threadIdx.x;
    const int l = t & 63, w = t >> 6;
    const int lane16 = l & 15, quad = l >> 4;
    const int m = blockIdx.x * 64 + w * 16 + lane16;
    const int dstart = blockIdx.y * KSLICE;

    f32x4 acc[8];
#pragma unroll
    for (int i = 0; i < 8; ++i) acc[i] = (f32x4){0.f, 0.f, 0.f, 0.f};

    const float* xrow = x + (size_t)m * D_N;
    const unsigned short* bhb = w1th + (size_t)lane16 * KPAD + quad * 8;
    const unsigned short* blb = w1tl + (size_t)lane16 * KPAD + quad * 8;

    for (int step = 0; step < 40; ++step) {
        const int kg = dstart + step * 32;
        if (kg >= D_N) break;               // wave-uniform, no LDS/sync in kernel
        const int kl = kg + quad * 8;
        float xv[8];
        if (kg + 32 <= D_N) {
            float4 v0 = *(const float4*)&xrow[kl];
            float4 v1 = *(const float4*)&xrow[kl + 4];
            xv[0] = v0.x; xv[1] = v0.y; xv[2] = v0.z; xv[3] = v0.w;
            xv[4] = v1.x; xv[5] = v1.y; xv[6] = v1.z; xv[7] = v1.w;
        } else {
#pragma unroll
            for (int j = 0; j < 8; ++j)
                xv[j] = (kl + j < D_N) ? xrow[kl + j] : 0.f;
        }
        half8 ah, al;
#pragma unroll
        for (int j = 0; j < 8; ++j) {
            float f = xv[j] * 2048.f;       // 2^11 pre-scale keeps lo terms normal
            _Float16 hv = (_Float16)f;
            ah[j] = hv;
            al[j] = (_Float16)(f - (float)hv);  // exact residual (Sterbenz)
        }
#pragma unroll
        for (int ni = 0; ni < 8; ++ni) {
            const size_t off = (size_t)ni * (16 * KPAD) + kg;
            half8 bh = *(const half8*)(bhb + off);
            half8 bl = *(const half8*)(blb + off);
            acc[ni] = __builtin_amdgcn_mfma_f32_16x16x32_f16(ah, bh, acc[ni], 0, 0, 0);
            acc[ni] = __builtin_amdgcn_mfma_f32_16x16x32_f16(al, bh, acc[ni], 0, 0, 0);
            acc[ni] = __builtin_amdgcn_mfma_f32_16x16x32_f16(ah, bl, acc[ni], 0, 0, 0);
        }
    }
    // C/D layout: col = lane&15 (B row = h), row = quad*4 + reg (A row = m)
    float* pb = part + (size_t)blockIdx.y * (B_N * H_N)
              + (size_t)(blockIdx.x * 64 + w * 16 + quad * 4) * H_N;
#pragma unroll
    for (int ni = 0; ni < 8; ++ni)
#pragma unroll
        for (int r = 0; r < 4; ++r)
            pb[(size_t)r * H_N + ni * 16 + lane16] = acc[ni][r];
}

// ---------------- kernel 3: reduce split-K + unscale (2^-22) + bias + relu ----------------
__global__ __launch_bounds__(256) void reduce_kernel(
        const float* __restrict__ part, const float* __restrict__ b1, float* __restrict__ h1) {
    int idx = blockIdx.x * 256 + threadIdx.x;  // < 524288
    int h = idx & 127;
    float s = 0.f;
#pragma unroll
    for (int ks = 0; ks < 8; ++ks) s += part[(size_t)ks * (B_N * H_N) + idx];
    h1[idx] = fmaxf(s * (1.0f / 4194304.0f) + b1[h], 0.f);
}

// ---------------- kernel 4: z_e, distances, t-kernel, argmax, z_q ----------------
__global__ __launch_bounds__(256) void cluster_kernel(
        const float* __restrict__ h1, const float* __restrict__ w2,
        const float* __restrict__ b2, const float* __restrict__ emb,
        float* __restrict__ out) {
    const int t = threadIdx.x;
    const int l = t & 63;
    const int m = blockIdx.x * 4 + (t >> 6);
    const int c = l & 31, half = l >> 5;
    const float* hrow = h1 + (size_t)m * H_N;
    float acc = 0.f;
#pragma unroll 8
    for (int j = 0; j < 64; ++j) {
        int hh = half * 64 + j;
        acc += hrow[hh] * w2[hh * Z_N + c];
    }
    acc += __shfl_xor(acc, 32);
    float z = acc + b2[c];
    if (l < 32) out[OUT_ZE + (size_t)m * Z_N + l] = z;

    const int k = l & 15, quad = l >> 4;
    float dk = 0.f;
#pragma unroll
    for (int j = 0; j < 8; ++j) {
        int cc = quad * 8 + j;
        float zc = __shfl(z, cc);
        float d = zc - emb[k * Z_N + cc];
        dk += d * d;
    }
    dk += __shfl_xor(dk, 16);
    dk += __shfl_xor(dk, 32);

    float p = powf(1.0f + dk * 0.1f, -5.5f);
    float s = p;
    s += __shfl_xor(s, 1); s += __shfl_xor(s, 2);
    s += __shfl_xor(s, 4); s += __shfl_xor(s, 8);
    float prob = p / s;

    int bi = 0;
    float best = __shfl(p, 0);
#pragma unroll
    for (int kk = 1; kk < 16; ++kk) {
        float pk = __shfl(p, kk);
        if (pk > best) { best = pk; bi = kk; }
    }
    if (l < 16) {
        out[OUT_ZD + (size_t)m * K_N + l] = dk;
        out[OUT_DP + (size_t)m * K_N + l] = prob;
    }
    if (l == 0) out[OUT_K + m] = (float)bi;
    if (l < 32) out[OUT_ZQ + (size_t)m * Z_N + l] = emb[bi * Z_N + l];
}

// ---------------- kernel 5: decoder L1 (both e and q) -> h bf16 ----------------
__global__ __launch_bounds__(256) void dec1_kernel(
        const float* __restrict__ out,
        const float* __restrict__ w1e, const float* __restrict__ b1e,
        const float* __restrict__ w1q, const float* __restrict__ b1q,
        unsigned short* __restrict__ he, unsigned short* __restrict__ hq) {
    int idx = blockIdx.x * 256 + threadIdx.x;  // < 524288
    int m = idx >> 7, h = idx & 127;
    const float* w1; const float* b1; const float* zrow; unsigned short* o;
    if (blockIdx.y == 0) { w1 = w1e; b1 = b1e; zrow = out + OUT_ZE; o = he; }
    else                 { w1 = w1q; b1 = b1q; zrow = out + OUT_ZQ; o = hq; }
    zrow += (size_t)m * Z_N;
    float acc = b1[h];
#pragma unroll 8
    for (int z = 0; z < Z_N; ++z) acc += zrow[z] * w1[z * H_N + h];
    o[idx] = f2bf(fmaxf(acc, 0.f));
}

// ---------------- kernel 6: decoder L2 bf16 MFMA GEMM, no LDS ----------------
__global__ __launch_bounds__(256) void dec2_kernel(
        const unsigned short* __restrict__ he, const unsigned short* __restrict__ hq,
        const unsigned short* __restrict__ w2te, const unsigned short* __restrict__ w2tq,
        const float* __restrict__ b2e, const float* __restrict__ b2q,
        float* __restrict__ out) {
    const unsigned short* hptr; const unsigned short* wt; const float* b2; float* o;
    if (blockIdx.z == 0) { hptr = he; wt = w2te; b2 = b2e; o = out + OUT_XE; }
    else                 { hptr = hq; wt = w2tq; b2 = b2q; o = out + OUT_XQ; }
    const int t = threadIdx.x;
    const int l = t & 63, w = t >> 6;
    const int m0 = blockIdx.x * 64;
    const int n0 = blockIdx.y * 256 + w * 64;
    if (n0 >= D_N) return;   // no __syncthreads in this kernel, safe
    const int lane16 = l & 15, quad = l >> 4;

    f32x4 acc[4][4];
#pragma unroll
    for (int i = 0; i < 4; ++i)
#pragma unroll
        for (int j = 0; j < 4; ++j) acc[i][j] = (f32x4){0.f, 0.f, 0.f, 0.f};

#pragma unroll
    for (int ks = 0; ks < 4; ++ks) {
        const int koff = ks * 32 + quad * 8;
        bf16x8 a[4], bb[4];
#pragma unroll
        for (int mi = 0; mi < 4; ++mi)
            a[mi] = *(const bf16x8*)&hptr[(size_t)(m0 + mi * 16 + lane16) * H_N + koff];
#pragma unroll
        for (int ni = 0; ni < 4; ++ni)
            bb[ni] = *(const bf16x8*)&wt[(size_t)(n0 + ni * 16 + lane16) * H_N + koff];
#pragma unroll
        for (int mi = 0; mi < 4; ++mi)
#pragma unroll
            for (int ni = 0; ni < 4; ++ni)
                acc[mi][ni] = __builtin_amdgcn_mfma_f32_16x16x32_bf16(
                    a[mi], bb[ni], acc[mi][ni], 0, 0, 0);
    }
#pragma unroll
    for (int ni = 0; ni < 4; ++ni) {
        int gn = n0 + ni * 16 + lane16;
        if (gn >= D_N) continue;
        float bias = b2[gn];
#pragma unroll
        for (int mi = 0; mi < 4; ++mi) {
            int gmb = m0 + mi * 16 + quad * 4;
#pragma unroll
            for (int r = 0; r < 4; ++r)
                o[(size_t)(gmb + r) * D_N + gn] = acc[mi][ni][r] + bias;
        }
    }
}

extern "C" void kernel_launch(void* const* d_in, const int* in_sizes, int n_in,
                              void* d_out, int out_size, void* d_ws, size_t ws_size,
                              hipStream_t stream) {
    const float* x      = (const float*)d_in[0];
    const float* enc_w1 = (const float*)d_in[1];
    const float* enc_b1 = (const float*)d_in[2];
    const float* enc_w2 = (const float*)d_in[3];
    const float* enc_b2 = (const float*)d_in[4];
    const float* emb    = (const float*)d_in[5];
    const float* de_w1  = (const float*)d_in[6];
    const float* de_b1  = (const float*)d_in[7];
    const float* de_w2  = (const float*)d_in[8];
    const float* de_b2  = (const float*)d_in[9];
    const float* dq_w1  = (const float*)d_in[10];
    const float* dq_b1  = (const float*)d_in[11];
    const float* dq_w2  = (const float*)d_in[12];
    const float* dq_b2  = (const float*)d_in[13];

    float* out = (float*)d_out;
    char* ws = (char*)d_ws;
    float* part           = (float*)(ws + WS_PART);
    float* h1             = (float*)(ws + WS_H1);
    unsigned short* he    = (unsigned short*)(ws + WS_HE);
    unsigned short* hq    = (unsigned short*)(ws + WS_HQ);
    unsigned short* w2te  = (unsigned short*)(ws + WS_W2TE);
    unsigned short* w2tq  = (unsigned short*)(ws + WS_W2TQ);
    // w1T hi/lo staged in d_out's x_e region (overwritten by dec2 afterwards)
    unsigned short* w1th  = (unsigned short*)out;
    unsigned short* w1tl  = (unsigned short*)out + (size_t)H_N * KPAD;

    w1t_kernel<<<dim3(KPAD / 64), 256, 0, stream>>>(enc_w1, (unsigned*)w1th, (unsigned*)w1tl);
    transpose_cvt_kernel<<<dim3(157, 2), 256, 0, stream>>>(de_w2, dq_w2,
                                                           (unsigned*)w2te, (unsigned*)w2tq);
    gemm1_kernel<<<dim3(64, 8), 256, 0, stream>>>(x, w1th, w1tl, part);
    reduce_kernel<<<2048, 256, 0, stream>>>(part, enc_b1, h1);
    cluster_kernel<<<1024, 256, 0, stream>>>(h1, enc_w2, enc_b2, emb, out);
    dec1_kernel<<<dim3(2048, 2), 256, 0, stream>>>(out, de_w1, de_b1, dq_w1, dq_b1, he, hq);
    dec2_kernel<<<dim3(64, 40, 2), 256, 0, stream>>>(he, hq, w2te, w2tq, de_b2, dq_b2, out);
}